// Round 13
// baseline (151.948 us; speedup 1.0000x reference)
//
#include <hip/hip_runtime.h>

// Problem constants (S == DIM == HID == 1024)
#define NH    8      // heads
#define NE    512    // experts per head-group (E)
#define NB    8      // batch
#define ND    1024   // DIM == HID == S
#define NROW  4096   // NB * NE  (rows of x)

typedef unsigned short u16;
typedef __attribute__((ext_vector_type(8))) short short8;
typedef __attribute__((ext_vector_type(4))) float f32x4;

__device__ __forceinline__ u16 f2bf(float f) {
  unsigned int u = __float_as_uint(f);
  u += 0x7fffu + ((u >> 16) & 1u);   // round-to-nearest-even
  return (u16)(u >> 16);
}

__device__ __forceinline__ void gload16(const u16* g, u16* l) {
  __builtin_amdgcn_global_load_lds(
      (const __attribute__((address_space(1))) unsigned int*)(const void*)g,
      (__attribute__((address_space(3))) unsigned int*)(void*)l, 16, 0, 0);
}

// ---------------------------------------------------------------------------
// Fused pre-kernel (round-7 verified, exact): scan2 [0,1024) |
// transpose_w [1024,3072) | convert_x [3072,7168).
// ---------------------------------------------------------------------------
__global__ __launch_bounds__(256) void fused_pre_kernel(
    const float* __restrict__ X, u16* __restrict__ Xb,
    const float* __restrict__ W, u16* __restrict__ Wt,
    const float* __restrict__ out_w, const float* __restrict__ mix_w,
    const float* __restrict__ mix_b, const float* __restrict__ proj_b,
    const float* __restrict__ out_b,
    u16* __restrict__ Afac, float* __restrict__ Kc) {
  __shared__ float tile[64][65];
  __shared__ float wsum[4];
  __shared__ float red[4];
  const int bz = blockIdx.x;
  const int t  = threadIdx.x;

  if (bz < 1024) {
    const int o = bz;
    const int lane = t & 63, wave = t >> 6;
    float ow[4];
#pragma unroll
    for (int k = 0; k < 4; ++k) ow[k] = out_w[(size_t)o * ND + 1023 - (4 * t + k)];
    float ob = out_b[o];
#pragma unroll 1
    for (int h = 0; h < NH; ++h) {
      const float* mwr = mix_w + (size_t)h * ND;
      const float* mbr = mix_b + (size_t)h * ND;
      const float* pbr = proj_b + (size_t)h * ND;
      float l[4];
      float run = 0.f, mbdot = 0.f;
#pragma unroll
      for (int k = 0; k < 4; ++k) {
        int j = 1023 - (4 * t + k);        // reversed order
        mbdot += ow[k] * mbr[j];
        run += ow[k] * mwr[j];
        l[k] = run;
      }
      float tsum = run;
      float sc = tsum;
#pragma unroll
      for (int d = 1; d < 64; d <<= 1) {
        float other = __shfl_up(sc, d);
        if (lane >= d) sc += other;
      }
      if (lane == 63) wsum[wave] = sc;
      __syncthreads();
      float wprefix = 0.f;
      for (int w = 0; w < wave; ++w) wprefix += wsum[w];
      float excl = wprefix + sc - tsum;

      float cdot = 0.f;
      ushort4 pack;
      u16* pk = (u16*)&pack;
#pragma unroll
      for (int k = 0; k < 4; ++k) {
        int d = 1023 - (4 * t + k);
        float a = excl + l[k];
        cdot += a * pbr[d];
        pk[3 - k] = f2bf(a);
      }
      *(ushort4*)(Afac + ((size_t)(h * ND + o)) * ND + (1020 - 4 * t)) = pack;

      float tot = cdot + mbdot;
#pragma unroll
      for (int m = 32; m >= 1; m >>= 1) tot += __shfl_xor(tot, m);
      if (lane == 0) red[wave] = tot;
      __syncthreads();
      if (t == 0) Kc[h * ND + o] = red[0] + red[1] + red[2] + red[3] + ob;
    }
  } else if (bz < 3072) {
    const int f  = bz - 1024;
    const int h  = f >> 8;
    const int d0 = ((f >> 4) & 15) * 64;
    const int s0 = (f & 15) * 64;
    const int tr = t >> 4;
    const int tc = t & 15;
#pragma unroll
    for (int i = 0; i < 4; ++i) {
      int d = tr + i * 16;
      float4 v = *(const float4*)(W + ((size_t)h * ND + d0 + d) * ND + s0 + tc * 4);
      tile[d][tc * 4 + 0] = v.x;
      tile[d][tc * 4 + 1] = v.y;
      tile[d][tc * 4 + 2] = v.z;
      tile[d][tc * 4 + 3] = v.w;
    }
    __syncthreads();
#pragma unroll
    for (int i = 0; i < 4; ++i) {
      int s  = tr + i * 16;
      int dd = tc * 4;
      ushort4 o;
      o.x = f2bf(tile[dd + 0][s]);
      o.y = f2bf(tile[dd + 1][s]);
      o.z = f2bf(tile[dd + 2][s]);
      o.w = f2bf(tile[dd + 3][s]);
      *(ushort4*)(Wt + ((size_t)h * ND + s0 + s) * ND + d0 + dd) = o;
    }
  } else {
    int i = (bz - 3072) * 256 + t;
    float4 v = ((const float4*)X)[i];
    ushort4 o;
    o.x = f2bf(v.x); o.y = f2bf(v.y); o.z = f2bf(v.z); o.w = f2bf(v.w);
    ((ushort4*)Xb)[i] = o;
  }
}

// ---------------------------------------------------------------------------
// Shared defs
// ---------------------------------------------------------------------------
#define MFMA_(d, a, b) d = __builtin_amdgcn_mfma_f32_16x16x32_bf16(a, b, d, 0, 0, 0)
#define NOVM ((void)0)
#define NOST ((void)0)
#define VM8 asm volatile("s_waitcnt vmcnt(8)" ::: "memory")
#define VM5 asm volatile("s_waitcnt vmcnt(5)" ::: "memory")
#define VM0 asm volatile("s_waitcnt vmcnt(0)" ::: "memory")

// BM=128 8-phase (gemm1, round-6/7 verified): per phase one mi, 2 A-reads, 8 MFMA.
#define PHASE1(q, b, STAGE_STMT, VMSTMT) do {                                  \
    short8 a0 = ldA(b, (q), 0);                                                \
    short8 a1 = ldA(b, (q), 1);                                                \
    if ((q) == 0) {                                                            \
      bf00 = ldB(b, 0, 0); bf01 = ldB(b, 0, 1);                                \
      bf10 = ldB(b, 1, 0); bf11 = ldB(b, 1, 1);                                \
      bf20 = ldB(b, 2, 0); bf21 = ldB(b, 2, 1);                                \
      bf30 = ldB(b, 3, 0); bf31 = ldB(b, 3, 1);                                \
    }                                                                          \
    STAGE_STMT;                                                                \
    __builtin_amdgcn_sched_barrier(0);                                         \
    VMSTMT;                                                                    \
    __builtin_amdgcn_s_barrier();                                              \
    asm volatile("s_waitcnt lgkmcnt(0)" ::: "memory");                         \
    __builtin_amdgcn_sched_barrier(0);                                         \
    __builtin_amdgcn_s_setprio(1);                                             \
    MFMA_(acc[(q)][0], a0, bf00);                                              \
    MFMA_(acc[(q)][1], a0, bf10);                                              \
    MFMA_(acc[(q)][2], a0, bf20);                                              \
    MFMA_(acc[(q)][3], a0, bf30);                                              \
    MFMA_(acc[(q)][0], a1, bf01);                                              \
    MFMA_(acc[(q)][1], a1, bf11);                                              \
    MFMA_(acc[(q)][2], a1, bf21);                                              \
    MFMA_(acc[(q)][3], a1, bf31);                                              \
    __builtin_amdgcn_s_setprio(0);                                             \
    __builtin_amdgcn_s_barrier();                                              \
  } while (0)

// ---------------------------------------------------------------------------
// Kernel 2: gemm1_8ph — BM=128, BN=256 8-phase (round-7 exact).
// ---------------------------------------------------------------------------
__global__ __launch_bounds__(512, 2) void gemm1_8ph(const u16* __restrict__ Afac,
                                                    const u16* __restrict__ Wt,
                                                    u16* __restrict__ Mmat) {
  __shared__ __align__(16) u16 lds[49152];
  const int h  = blockIdx.z;
  const int m0 = blockIdx.y * 128;
  const int n0 = blockIdx.x * 256;
  const int tid  = threadIdx.x;
  const int lane = tid & 63;
  const int wave = tid >> 6;
  const int wm   = wave >> 2;
  const int wn   = wave & 3;
  const int li8 = lane >> 3;
  const int lc  = (lane & 7) ^ li8;
  const size_t stSrc = (size_t)li8 * ND + lc * 8;
  const int stDst = lane * 8;
  const u16* aSrc = Afac + ((size_t)h * ND + m0) * ND + stSrc;
  const u16* bSrc = Wt + ((size_t)h * ND + n0) * ND + stSrc;
  const int fr  = lane & 15;
  const int rg  = lane >> 4;
  const int ca0 = (((lane >> 4)    ) ^ (lane & 7)) * 8;
  const int ca1 = (((lane >> 4) + 4) ^ (lane & 7)) * 8;
  const int aOff = (wm * 64 + fr) * 64;
  const int bOff = 8192 + (wn * 64 + fr) * 64;

  auto stageA = [&](int h2, int t, int b) {
    int R = (wave >> 2) * 64 + h2 * 32 + (wave & 3) * 8;
    gload16(aSrc + (size_t)R * ND + t * 64, lds + b * 24576 + R * 64 + stDst);
  };
  auto stageB = [&](int h2, int t, int b) {
#pragma unroll
    for (int jj = 0; jj < 2; ++jj) {
      int j = 2 * wave + jj;
      int R = h2 * 128 + j * 8;
      gload16(bSrc + (size_t)R * ND + t * 64, lds + b * 24576 + 8192 + R * 64 + stDst);
    }
  };
  auto ldA = [&](int b, int mi, int kk) -> short8 {
    return *(const short8*)(lds + b * 24576 + aOff + mi * 1024 + (kk ? ca1 : ca0));
  };
  auto ldB = [&](int b, int ni, int kk) -> short8 {
    return *(const short8*)(lds + b * 24576 + bOff + ni * 1024 + (kk ? ca1 : ca0));
  };

  f32x4 acc[4][4];
  f32x4 z = {0.f, 0.f, 0.f, 0.f};
#pragma unroll
  for (int i = 0; i < 4; ++i)
#pragma unroll
    for (int j = 0; j < 4; ++j) acc[i][j] = z;
  short8 bf00, bf01, bf10, bf11, bf20, bf21, bf30, bf31;

  stageA(0, 0, 0); stageA(1, 0, 0);
  stageB(0, 0, 0); stageB(1, 0, 0);
  stageB(0, 1, 1); stageB(1, 1, 1);
  stageA(0, 1, 1);
  VM5;
  __builtin_amdgcn_s_barrier();

#pragma unroll 1
  for (int it = 0; it < 7; ++it) {
    const int T = 2 * it;
    PHASE1(0, 0, stageA(1, T + 1, 1), NOVM);
    PHASE1(1, 0, stageB(0, T + 2, 0), NOVM);
    PHASE1(2, 0, stageB(1, T + 2, 0), NOVM);
    PHASE1(3, 0, stageA(0, T + 2, 0), VM5);
    PHASE1(0, 1, stageA(1, T + 2, 0), NOVM);
    PHASE1(1, 1, stageB(0, T + 3, 1), NOVM);
    PHASE1(2, 1, stageB(1, T + 3, 1), NOVM);
    PHASE1(3, 1, stageA(0, T + 3, 1), VM5);
  }
  PHASE1(0, 0, stageA(1, 15, 1), NOVM);
  PHASE1(1, 0, NOVM, NOVM);
  PHASE1(2, 0, NOVM, NOVM);
  PHASE1(3, 0, NOVM, VM0);
  PHASE1(0, 1, NOVM, NOVM);
  PHASE1(1, 1, NOVM, NOVM);
  PHASE1(2, 1, NOVM, NOVM);
  PHASE1(3, 1, NOVM, NOVM);

  u16* Mh = Mmat + (size_t)h * ND * ND;
  const int r0 = m0 + wm * 64 + rg * 4;
  const int c0 = n0 + wn * 64 + fr;
#pragma unroll
  for (int mi = 0; mi < 4; ++mi) {
#pragma unroll
    for (int r = 0; r < 4; ++r) {
      u16* orow = Mh + (size_t)(r0 + mi * 16 + r) * ND + c0;
#pragma unroll
      for (int ni = 0; ni < 4; ++ni)
        orow[ni * 16] = f2bf(acc[mi][ni][r]);
    }
  }
}

// ---------------------------------------------------------------------------
// Kernel 3: gemm2e — B-OPERAND IN REGISTERS (DS-pipe offload).
// r7 structure/geometry (BM=256, BN=256, BK=64, 8 waves 2Mx4N, rect XCD
// swizzle, 8-phase barriers, A via gload16+swizzled LDS) but B fragments are
// loaded global->register (wave-private), double-buffered in named sets
// bA*/bB* with a 2-tile unroll. DS traffic/K-tile: 256KB -> 160KB (-37%).
// Pipeline: B(t+2) issued after tile-t ph3 MFMAs (reg reuse legal, ~4-phase
// cover); A(t+1) staged ph0/ph1 into free buffer; vmcnt(8) at tile end
// leaves exactly the 8 just-issued B-loads (FIFO-verified incl. tails).
// ---------------------------------------------------------------------------
#define PHASEE(q, b, ISSUE_STMT, BP) do {                                      \
    short8 a00 = ldA(b, 2*(q),     0);                                         \
    short8 a01 = ldA(b, 2*(q),     1);                                         \
    short8 a10 = ldA(b, 2*(q) + 1, 0);                                         \
    short8 a11 = ldA(b, 2*(q) + 1, 1);                                         \
    ISSUE_STMT;                                                                \
    __builtin_amdgcn_sched_barrier(0);                                         \
    __builtin_amdgcn_s_barrier();                                              \
    asm volatile("s_waitcnt lgkmcnt(0)" ::: "memory");                         \
    __builtin_amdgcn_sched_barrier(0);                                         \
    __builtin_amdgcn_s_setprio(1);                                             \
    MFMA_(acc[2*(q)  ][0], a00, BP##00);                                       \
    MFMA_(acc[2*(q)  ][1], a00, BP##10);                                       \
    MFMA_(acc[2*(q)  ][2], a00, BP##20);                                       \
    MFMA_(acc[2*(q)  ][3], a00, BP##30);                                       \
    MFMA_(acc[2*(q)+1][0], a10, BP##00);                                       \
    MFMA_(acc[2*(q)+1][1], a10, BP##10);                                       \
    MFMA_(acc[2*(q)+1][2], a10, BP##20);                                       \
    MFMA_(acc[2*(q)+1][3], a10, BP##30);                                       \
    MFMA_(acc[2*(q)  ][0], a01, BP##01);                                       \
    MFMA_(acc[2*(q)  ][1], a01, BP##11);                                       \
    MFMA_(acc[2*(q)  ][2], a01, BP##21);                                       \
    MFMA_(acc[2*(q)  ][3], a01, BP##31);                                       \
    MFMA_(acc[2*(q)+1][0], a11, BP##01);                                       \
    MFMA_(acc[2*(q)+1][1], a11, BP##11);                                       \
    MFMA_(acc[2*(q)+1][2], a11, BP##21);                                       \
    MFMA_(acc[2*(q)+1][3], a11, BP##31);                                       \
    __builtin_amdgcn_s_setprio(0);                                             \
    __builtin_amdgcn_s_barrier();                                              \
  } while (0)

// ph3 variant: B-issue AFTER the MFMAs (register reuse), then counted wait.
#define PHASEE_LAST(b, POST_STMT, VMSTMT, BP) do {                             \
    short8 a00 = ldA(b, 6, 0);                                                 \
    short8 a01 = ldA(b, 6, 1);                                                 \
    short8 a10 = ldA(b, 7, 0);                                                 \
    short8 a11 = ldA(b, 7, 1);                                                 \
    __builtin_amdgcn_s_barrier();                                              \
    asm volatile("s_waitcnt lgkmcnt(0)" ::: "memory");                         \
    __builtin_amdgcn_sched_barrier(0);                                         \
    __builtin_amdgcn_s_setprio(1);                                             \
    MFMA_(acc[6][0], a00, BP##00);                                             \
    MFMA_(acc[6][1], a00, BP##10);                                             \
    MFMA_(acc[6][2], a00, BP##20);                                             \
    MFMA_(acc[6][3], a00, BP##30);                                             \
    MFMA_(acc[7][0], a10, BP##00);                                             \
    MFMA_(acc[7][1], a10, BP##10);                                             \
    MFMA_(acc[7][2], a10, BP##20);                                             \
    MFMA_(acc[7][3], a10, BP##30);                                             \
    MFMA_(acc[6][0], a01, BP##01);                                             \
    MFMA_(acc[6][1], a01, BP##11);                                             \
    MFMA_(acc[6][2], a01, BP##21);                                             \
    MFMA_(acc[6][3], a01, BP##31);                                             \
    MFMA_(acc[7][0], a11, BP##01);                                             \
    MFMA_(acc[7][1], a11, BP##11);                                             \
    MFMA_(acc[7][2], a11, BP##21);                                             \
    MFMA_(acc[7][3], a11, BP##31);                                             \
    __builtin_amdgcn_s_setprio(0);                                             \
    POST_STMT;                                                                 \
    __builtin_amdgcn_sched_barrier(0);                                         \
    VMSTMT;                                                                    \
    __builtin_amdgcn_s_barrier();                                              \
  } while (0)

#define LOADB(BP, t) do {                                                      \
    BP##00 = lgB(t, 0, 0); BP##01 = lgB(t, 0, 1);                              \
    BP##10 = lgB(t, 1, 0); BP##11 = lgB(t, 1, 1);                              \
    BP##20 = lgB(t, 2, 0); BP##21 = lgB(t, 2, 1);                              \
    BP##30 = lgB(t, 3, 0); BP##31 = lgB(t, 3, 1);                              \
  } while (0)

__global__ __launch_bounds__(512, 2) void gemm2e(const u16* __restrict__ Xb,
                                                 const u16* __restrict__ Bm,
                                                 const float* __restrict__ Kc,
                                                 float* __restrict__ Out) {
  __shared__ __align__(16) u16 lds[32768];   // A only: 2 bufs x 256x64 u16
  const int tid  = threadIdx.x;
  const int lane = tid & 63;
  const int wave = tid >> 6;
  const int wm   = wave >> 2;
  const int wn   = wave & 3;

  // Rect XCD swizzle (round-7, FETCH-verified)
  const int bid = blockIdx.x;
  const int xcd = bid & 7;
  const int loc = bid >> 3;
  const int m0  = (((xcd >> 2) << 3) + (loc >> 3)) * 256;
  const int n0  = (((xcd & 3) << 3) + (loc & 7)) * 256;

  // A staging (round-7 exact, swizzled source, linear LDS dst)
  const int li8 = lane >> 3;
  const int lc  = (lane & 7) ^ li8;
  const size_t stSrc = (size_t)li8 * ND + lc * 8;
  const int stDst = lane * 8;
  const u16* aSrc = Xb + (size_t)m0 * ND + stSrc;

  auto stageA = [&](int h, int t, int b) {
#pragma unroll
    for (int jj = 0; jj < 2; ++jj) {
      int j = 2 * wave + jj;
      int R = ((j >> 3) << 7) + h * 64 + ((j & 7) << 3);
      gload16(aSrc + (size_t)R * ND + t * 64, lds + b * 16384 + R * 64 + stDst);
    }
  };

  const int fr  = lane & 15;
  const int rg  = lane >> 4;
  const int ca0 = (((lane >> 4)    ) ^ (lane & 7)) * 8;
  const int ca1 = (((lane >> 4) + 4) ^ (lane & 7)) * 8;
  const int aOff = (wm * 128 + fr) * 64;

  auto ldA = [&](int b, int mi, int kk) -> short8 {
    return *(const short8*)(lds + b * 16384 + aOff + mi * 1024 + (kk ? ca1 : ca0));
  };

  // B: wave-private global->register fragment loads (identical logical data
  // to r7's LDS path; swizzle cancels: col = t*64 + kk*32 + (lane>>4)*8).
  const u16* bRow = Bm + (size_t)(n0 + wn * 64 + fr) * ND + (lane >> 4) * 8;
  auto lgB = [&](int t, int ni, int kk) -> short8 {
    return *(const short8*)(bRow + ni * 16 * ND + t * 64 + kk * 32);
  };

  f32x4 acc[8][4];
  f32x4 z = {0.f, 0.f, 0.f, 0.f};
#pragma unroll
  for (int i = 0; i < 8; ++i)
#pragma unroll
    for (int j = 0; j < 4; ++j) acc[i][j] = z;

  short8 bA00, bA01, bA10, bA11, bA20, bA21, bA30, bA31;
  short8 bB00, bB01, bB10, bB11, bB20, bB21, bB30, bB31;

  // Prologue: B(0)->bA (8), A(0)->buf0 (4), B(1)->bB (8); drain to 8 (bB left).
  LOADB(bA, 0);
  stageA(0, 0, 0); stageA(1, 0, 0);
  LOADB(bB, 1);
  VM8;
  __builtin_amdgcn_s_barrier();

  // Tiles 0..13 uniform (A(t+1) at ph0/1; B(t+2) after ph3 MFMAs; VM8).
#pragma unroll 1
  for (int it = 0; it < 7; ++it) {
    const int T = 2 * it;
    // tile T (even): buf0, consume bA; stage A(T+1)->buf1; B(T+2)->bA.
    PHASEE(0, 0, stageA(0, T + 1, 1), bA);
    PHASEE(1, 0, stageA(1, T + 1, 1), bA);
    PHASEE(2, 0, NOST, bA);
    PHASEE_LAST(0, LOADB(bA, T + 2), VM8, bA);
    // tile T+1 (odd): buf1, consume bB; stage A(T+2)->buf0; B(T+3)->bB.
    PHASEE(0, 1, stageA(0, T + 2, 0), bB);
    PHASEE(1, 1, stageA(1, T + 2, 0), bB);
    PHASEE(2, 1, NOST, bB);
    PHASEE_LAST(1, LOADB(bB, T + 3), VM8, bB);
  }
  // tile 14 (even, buf0, bA): stage A(15)->buf1; no B; VM0 drains B(15)+A(15).
  PHASEE(0, 0, stageA(0, 15, 1), bA);
  PHASEE(1, 0, stageA(1, 15, 1), bA);
  PHASEE(2, 0, NOST, bA);
  PHASEE_LAST(0, NOST, VM0, bA);
  // tile 15 (odd, buf1, bB): nothing outstanding.
  PHASEE(0, 1, NOST, bB);
  PHASEE(1, 1, NOST, bB);
  PHASEE(2, 1, NOST, bB);
  PHASEE_LAST(1, NOST, NOVM, bB);

  // Epilogue (round-7 exact): bias + b/h/e remap, direct stores.
  const int hH = n0 >> 10;
  const int r0 = m0 + wm * 128 + rg * 4;
  const int c0 = n0 + wn * 64 + fr;
  const int o0 = c0 & 1023;
  float bias[4];
#pragma unroll
  for (int ni = 0; ni < 4; ++ni) bias[ni] = Kc[c0 + ni * 16];
#pragma unroll
  for (int mi = 0; mi < 8; ++mi) {
#pragma unroll
    for (int r = 0; r < 4; ++r) {
      int rb = r0 + mi * 16 + r;              // global x row = b*512 + e
      float* orow = Out + ((size_t)(rb >> 9) * 4096 + hH * 512 + (rb & 511)) * 1024 + o0;
#pragma unroll
      for (int ni = 0; ni < 4; ++ni)
        orow[ni * 16] = acc[mi][ni][r] + bias[ni];
    }
  }
}

// ---------------------------------------------------------------------------
extern "C" void kernel_launch(void* const* d_in, const int* in_sizes, int n_in,
                              void* d_out, int out_size, void* d_ws, size_t ws_size,
                              hipStream_t stream) {
  (void)in_sizes; (void)n_in; (void)out_size; (void)ws_size;
  const float* x      = (const float*)d_in[0];
  const float* proj_w = (const float*)d_in[1];
  const float* proj_b = (const float*)d_in[2];
  const float* mix_w  = (const float*)d_in[3];
  const float* mix_b  = (const float*)d_in[4];
  const float* out_w  = (const float*)d_in[5];
  const float* out_b  = (const float*)d_in[6];
  float* Out = (float*)d_out;

  // Scratch carved from d_out (dead before gemm2 writes Out): Wt, Afac
  u16* Wt   = (u16*)d_out;
  u16* Afac = (u16*)d_out + (size_t)8 * 1024 * 1024;
  // Scratch in d_ws: Xb (8 MiB) + Mmat (16 MiB) + Kc (32 KiB)
  u16*   Xb   = (u16*)d_ws;
  u16*   Mmat = (u16*)((char*)d_ws + ((size_t)8 << 20));
  float* Kc   = (float*)((char*)d_ws + ((size_t)24 << 20));

  fused_pre_kernel<<<7168, 256, 0, stream>>>(x, Xb, proj_w, Wt,
                                             out_w, mix_w, mix_b, proj_b, out_b,
                                             Afac, Kc);
  gemm1_8ph<<<dim3(4, 8, NH), 512, 0, stream>>>(Afac, Wt, Mmat);
  gemm2e<<<512, 512, 0, stream>>>(Xb, Mmat, Kc, Out);
}

// Round 14
// 114.564 us; speedup vs baseline: 1.3263x; 1.3263x over previous
//
#include <hip/hip_runtime.h>

// Problem constants (S == DIM == HID == 1024)
#define NH    8      // heads
#define NE    512    // experts per head-group (E)
#define NB    8      // batch
#define ND    1024   // DIM == HID == S
#define NROW  4096   // NB * NE  (rows of x)

typedef unsigned short u16;
typedef __attribute__((ext_vector_type(8))) short short8;
typedef __attribute__((ext_vector_type(4))) float f32x4;

__device__ __forceinline__ u16 f2bf(float f) {
  unsigned int u = __float_as_uint(f);
  u += 0x7fffu + ((u >> 16) & 1u);   // round-to-nearest-even
  return (u16)(u >> 16);
}

__device__ __forceinline__ void gload16(const u16* g, u16* l) {
  __builtin_amdgcn_global_load_lds(
      (const __attribute__((address_space(1))) unsigned int*)(const void*)g,
      (__attribute__((address_space(3))) unsigned int*)(void*)l, 16, 0, 0);
}

// ---------------------------------------------------------------------------
// Fused pre-kernel (round-7 verified): scan2 (blocks [0,1024)) |
// transpose_w ([1024,3072)) | convert_x ([3072,7168)).
// ---------------------------------------------------------------------------
__global__ __launch_bounds__(256) void fused_pre_kernel(
    const float* __restrict__ X, u16* __restrict__ Xb,
    const float* __restrict__ W, u16* __restrict__ Wt,
    const float* __restrict__ out_w, const float* __restrict__ mix_w,
    const float* __restrict__ mix_b, const float* __restrict__ proj_b,
    const float* __restrict__ out_b,
    u16* __restrict__ Afac, float* __restrict__ Kc) {
  __shared__ float tile[64][65];   // transpose branch
  __shared__ float wsum[4];        // scan branch
  __shared__ float red[4];
  const int bz = blockIdx.x;
  const int t  = threadIdx.x;

  if (bz < 1024) {
    // ---- scan2: one block per o; loop h; out_w row read once ----
    const int o = bz;
    const int lane = t & 63, wave = t >> 6;
    float ow[4];
#pragma unroll
    for (int k = 0; k < 4; ++k) ow[k] = out_w[(size_t)o * ND + 1023 - (4 * t + k)];
    float ob = out_b[o];
#pragma unroll 1
    for (int h = 0; h < NH; ++h) {
      const float* mwr = mix_w + (size_t)h * ND;
      const float* mbr = mix_b + (size_t)h * ND;
      const float* pbr = proj_b + (size_t)h * ND;
      float l[4];
      float run = 0.f, mbdot = 0.f;
#pragma unroll
      for (int k = 0; k < 4; ++k) {
        int j = 1023 - (4 * t + k);        // reversed order
        mbdot += ow[k] * mbr[j];
        run += ow[k] * mwr[j];
        l[k] = run;
      }
      float tsum = run;
      float sc = tsum;
#pragma unroll
      for (int d = 1; d < 64; d <<= 1) {
        float other = __shfl_up(sc, d);
        if (lane >= d) sc += other;
      }
      if (lane == 63) wsum[wave] = sc;
      __syncthreads();
      float wprefix = 0.f;
      for (int w = 0; w < wave; ++w) wprefix += wsum[w];
      float excl = wprefix + sc - tsum;

      float cdot = 0.f;
      ushort4 pack;
      u16* pk = (u16*)&pack;
#pragma unroll
      for (int k = 0; k < 4; ++k) {
        int d = 1023 - (4 * t + k);
        float a = excl + l[k];
        cdot += a * pbr[d];
        pk[3 - k] = f2bf(a);
      }
      *(ushort4*)(Afac + ((size_t)(h * ND + o)) * ND + (1020 - 4 * t)) = pack;

      float tot = cdot + mbdot;
#pragma unroll
      for (int m = 32; m >= 1; m >>= 1) tot += __shfl_xor(tot, m);
      if (lane == 0) red[wave] = tot;
      __syncthreads();
      if (t == 0) Kc[h * ND + o] = red[0] + red[1] + red[2] + red[3] + ob;
    }
  } else if (bz < 3072) {
    // ---- transpose_w: Wt[h][s][d] = bf16(W[h][d][s]) ----
    const int f  = bz - 1024;
    const int h  = f >> 8;
    const int d0 = ((f >> 4) & 15) * 64;
    const int s0 = (f & 15) * 64;
    const int tr = t >> 4;
    const int tc = t & 15;
#pragma unroll
    for (int i = 0; i < 4; ++i) {
      int d = tr + i * 16;
      float4 v = *(const float4*)(W + ((size_t)h * ND + d0 + d) * ND + s0 + tc * 4);
      tile[d][tc * 4 + 0] = v.x;
      tile[d][tc * 4 + 1] = v.y;
      tile[d][tc * 4 + 2] = v.z;
      tile[d][tc * 4 + 3] = v.w;
    }
    __syncthreads();
#pragma unroll
    for (int i = 0; i < 4; ++i) {
      int s  = tr + i * 16;
      int dd = tc * 4;
      ushort4 o;
      o.x = f2bf(tile[dd + 0][s]);
      o.y = f2bf(tile[dd + 1][s]);
      o.z = f2bf(tile[dd + 2][s]);
      o.w = f2bf(tile[dd + 3][s]);
      *(ushort4*)(Wt + ((size_t)h * ND + s0 + s) * ND + d0 + dd) = o;
    }
  } else {
    // ---- convert_x: f32 -> bf16, float4 granularity ----
    int i = (bz - 3072) * 256 + t;
    float4 v = ((const float4*)X)[i];
    ushort4 o;
    o.x = f2bf(v.x); o.y = f2bf(v.y); o.z = f2bf(v.z); o.w = f2bf(v.w);
    ((ushort4*)Xb)[i] = o;
  }
}

// ---------------------------------------------------------------------------
// Shared defs for 8-phase cores (round-7 verified schedule).
// ---------------------------------------------------------------------------
#define MFMA_(d, a, b) d = __builtin_amdgcn_mfma_f32_16x16x32_bf16(a, b, d, 0, 0, 0)
#define NOVM ((void)0)
#define VM6 asm volatile("s_waitcnt vmcnt(6)" ::: "memory")
#define VM5 asm volatile("s_waitcnt vmcnt(5)" ::: "memory")
#define VM0 asm volatile("s_waitcnt vmcnt(0)" ::: "memory")

#define PHASE(q, b, STAGE_STMT, VMSTMT) do {                                   \
    short8 a00 = ldA(b, 2*(q),     0);                                         \
    short8 a01 = ldA(b, 2*(q),     1);                                         \
    short8 a10 = ldA(b, 2*(q) + 1, 0);                                         \
    short8 a11 = ldA(b, 2*(q) + 1, 1);                                         \
    if ((q) == 0) {                                                            \
      bf00 = ldB(b, 0, 0); bf01 = ldB(b, 0, 1);                                \
      bf10 = ldB(b, 1, 0); bf11 = ldB(b, 1, 1);                                \
      bf20 = ldB(b, 2, 0); bf21 = ldB(b, 2, 1);                                \
      bf30 = ldB(b, 3, 0); bf31 = ldB(b, 3, 1);                                \
    }                                                                          \
    STAGE_STMT;                                                                \
    __builtin_amdgcn_sched_barrier(0);                                         \
    VMSTMT;                                                                    \
    __builtin_amdgcn_s_barrier();                                              \
    asm volatile("s_waitcnt lgkmcnt(0)" ::: "memory");                         \
    __builtin_amdgcn_sched_barrier(0);                                         \
    __builtin_amdgcn_s_setprio(1);                                             \
    MFMA_(acc[2*(q)  ][0], a00, bf00);                                         \
    MFMA_(acc[2*(q)  ][1], a00, bf10);                                         \
    MFMA_(acc[2*(q)  ][2], a00, bf20);                                         \
    MFMA_(acc[2*(q)  ][3], a00, bf30);                                         \
    MFMA_(acc[2*(q)+1][0], a10, bf00);                                         \
    MFMA_(acc[2*(q)+1][1], a10, bf10);                                         \
    MFMA_(acc[2*(q)+1][2], a10, bf20);                                         \
    MFMA_(acc[2*(q)+1][3], a10, bf30);                                         \
    MFMA_(acc[2*(q)  ][0], a01, bf01);                                         \
    MFMA_(acc[2*(q)  ][1], a01, bf11);                                         \
    MFMA_(acc[2*(q)  ][2], a01, bf21);                                         \
    MFMA_(acc[2*(q)  ][3], a01, bf31);                                         \
    MFMA_(acc[2*(q)+1][0], a11, bf01);                                         \
    MFMA_(acc[2*(q)+1][1], a11, bf11);                                         \
    MFMA_(acc[2*(q)+1][2], a11, bf21);                                         \
    MFMA_(acc[2*(q)+1][3], a11, bf31);                                         \
    __builtin_amdgcn_s_setprio(0);                                             \
    __builtin_amdgcn_s_barrier();                                              \
  } while (0)

// BM=128 variant: per phase one mi (=q), 2 A-reads, 8 MFMA.
#define PHASE1(q, b, STAGE_STMT, VMSTMT) do {                                  \
    short8 a0 = ldA(b, (q), 0);                                                \
    short8 a1 = ldA(b, (q), 1);                                                \
    if ((q) == 0) {                                                            \
      bf00 = ldB(b, 0, 0); bf01 = ldB(b, 0, 1);                                \
      bf10 = ldB(b, 1, 0); bf11 = ldB(b, 1, 1);                                \
      bf20 = ldB(b, 2, 0); bf21 = ldB(b, 2, 1);                                \
      bf30 = ldB(b, 3, 0); bf31 = ldB(b, 3, 1);                                \
    }                                                                          \
    STAGE_STMT;                                                                \
    __builtin_amdgcn_sched_barrier(0);                                         \
    VMSTMT;                                                                    \
    __builtin_amdgcn_s_barrier();                                              \
    asm volatile("s_waitcnt lgkmcnt(0)" ::: "memory");                         \
    __builtin_amdgcn_sched_barrier(0);                                         \
    __builtin_amdgcn_s_setprio(1);                                             \
    MFMA_(acc[(q)][0], a0, bf00);                                              \
    MFMA_(acc[(q)][1], a0, bf10);                                              \
    MFMA_(acc[(q)][2], a0, bf20);                                              \
    MFMA_(acc[(q)][3], a0, bf30);                                              \
    MFMA_(acc[(q)][0], a1, bf01);                                              \
    MFMA_(acc[(q)][1], a1, bf11);                                              \
    MFMA_(acc[(q)][2], a1, bf21);                                              \
    MFMA_(acc[(q)][3], a1, bf31);                                              \
    __builtin_amdgcn_s_setprio(0);                                             \
    __builtin_amdgcn_s_barrier();                                              \
  } while (0)

// Common body for BM=256 (gemm2), verified rounds 2/5/6/7.
#define GEMM_8PH_BODY(ASRC, BSRC)                                              \
  const int tid  = threadIdx.x;                                                \
  const int lane = tid & 63;                                                   \
  const int wave = tid >> 6;                                                   \
  const int wm   = wave >> 2;                                                  \
  const int wn   = wave & 3;                                                   \
  const int li8 = lane >> 3;                                                   \
  const int lc  = (lane & 7) ^ li8;                                            \
  const size_t stSrc = (size_t)li8 * ND + lc * 8;                              \
  const int stDst = lane * 8;                                                  \
  const u16* aSrc = (ASRC) + stSrc;                                            \
  const u16* bSrc = (BSRC) + stSrc;                                            \
  const int fr  = lane & 15;                                                   \
  const int rg  = lane >> 4;                                                   \
  const int ca0 = (((lane >> 4)    ) ^ (lane & 7)) * 8;                        \
  const int ca1 = (((lane >> 4) + 4) ^ (lane & 7)) * 8;                        \
  const int aOff = (wm * 128 + fr) * 64;                                       \
  const int bOff = 16384 + (wn * 64 + fr) * 64;                                \
  auto stageA = [&](int h, int t, int b) {                                     \
    _Pragma("unroll")                                                          \
    for (int jj = 0; jj < 2; ++jj) {                                           \
      int j = 2 * wave + jj;                                                   \
      int R = ((j >> 3) << 7) + h * 64 + ((j & 7) << 3);                       \
      gload16(aSrc + (size_t)R * ND + t * 64, lds + b * 32768 + R * 64 + stDst); \
    }                                                                          \
  };                                                                           \
  auto stageB = [&](int h, int t, int b) {                                     \
    _Pragma("unroll")                                                          \
    for (int jj = 0; jj < 2; ++jj) {                                           \
      int j = 2 * wave + jj;                                                   \
      int R = h * 128 + j * 8;                                                 \
      gload16(bSrc + (size_t)R * ND + t * 64, lds + b * 32768 + 16384 + R * 64 + stDst); \
    }                                                                          \
  };                                                                           \
  auto ldA = [&](int b, int mi, int kk) -> short8 {                            \
    return *(const short8*)(lds + b * 32768 + aOff + mi * 1024 + (kk ? ca1 : ca0)); \
  };                                                                           \
  auto ldB = [&](int b, int ni, int kk) -> short8 {                            \
    return *(const short8*)(lds + b * 32768 + bOff + ni * 1024 + (kk ? ca1 : ca0)); \
  };                                                                           \
  f32x4 acc[8][4];                                                             \
  f32x4 z = {0.f, 0.f, 0.f, 0.f};                                              \
  _Pragma("unroll")                                                            \
  for (int i = 0; i < 8; ++i)                                                  \
    _Pragma("unroll")                                                          \
    for (int j = 0; j < 4; ++j) acc[i][j] = z;                                 \
  short8 bf00, bf01, bf10, bf11, bf20, bf21, bf30, bf31;                       \
  stageA(0, 0, 0); stageA(1, 0, 0);                                            \
  stageB(0, 0, 0); stageB(1, 0, 0);                                            \
  stageB(0, 1, 1); stageB(1, 1, 1);                                            \
  stageA(0, 1, 1);                                                             \
  asm volatile("s_waitcnt vmcnt(6)" ::: "memory");                             \
  __builtin_amdgcn_s_barrier();                                                \
  _Pragma("unroll 1")                                                          \
  for (int it = 0; it < 7; ++it) {                                             \
    const int T = 2 * it;                                                      \
    PHASE(0, 0, stageA(1, T + 1, 1), NOVM);                                    \
    PHASE(1, 0, stageB(0, T + 2, 0), NOVM);                                    \
    PHASE(2, 0, stageB(1, T + 2, 0), NOVM);                                    \
    PHASE(3, 0, stageA(0, T + 2, 0), VM6);                                     \
    PHASE(0, 1, stageA(1, T + 2, 0), NOVM);                                    \
    PHASE(1, 1, stageB(0, T + 3, 1), NOVM);                                    \
    PHASE(2, 1, stageB(1, T + 3, 1), NOVM);                                    \
    PHASE(3, 1, stageA(0, T + 3, 1), VM6);                                     \
  }                                                                            \
  PHASE(0, 0, stageA(1, 15, 1), NOVM);                                         \
  PHASE(1, 0, NOVM, NOVM);                                                     \
  PHASE(2, 0, NOVM, NOVM);                                                     \
  PHASE(3, 0, NOVM, VM0);                                                      \
  PHASE(0, 1, NOVM, NOVM);                                                     \
  PHASE(1, 1, NOVM, NOVM);                                                     \
  PHASE(2, 1, NOVM, NOVM);                                                     \
  PHASE(3, 1, NOVM, NOVM);

// ---------------------------------------------------------------------------
// Kernel 4: gemm1_8ph — BM=128, BN=256 8-phase (round-6/7 verified).
// ---------------------------------------------------------------------------
__global__ __launch_bounds__(512, 2) void gemm1_8ph(const u16* __restrict__ Afac,
                                                    const u16* __restrict__ Wt,
                                                    u16* __restrict__ Mmat) {
  __shared__ __align__(16) u16 lds[49152];
  const int h  = blockIdx.z;
  const int m0 = blockIdx.y * 128;
  const int n0 = blockIdx.x * 256;
  const int tid  = threadIdx.x;
  const int lane = tid & 63;
  const int wave = tid >> 6;
  const int wm   = wave >> 2;
  const int wn   = wave & 3;
  const int li8 = lane >> 3;
  const int lc  = (lane & 7) ^ li8;
  const size_t stSrc = (size_t)li8 * ND + lc * 8;
  const int stDst = lane * 8;
  const u16* aSrc = Afac + ((size_t)h * ND + m0) * ND + stSrc;
  const u16* bSrc = Wt + ((size_t)h * ND + n0) * ND + stSrc;
  const int fr  = lane & 15;
  const int rg  = lane >> 4;
  const int ca0 = (((lane >> 4)    ) ^ (lane & 7)) * 8;
  const int ca1 = (((lane >> 4) + 4) ^ (lane & 7)) * 8;
  const int aOff = (wm * 64 + fr) * 64;
  const int bOff = 8192 + (wn * 64 + fr) * 64;

  auto stageA = [&](int h2, int t, int b) {
    int R = (wave >> 2) * 64 + h2 * 32 + (wave & 3) * 8;
    gload16(aSrc + (size_t)R * ND + t * 64, lds + b * 24576 + R * 64 + stDst);
  };
  auto stageB = [&](int h2, int t, int b) {
#pragma unroll
    for (int jj = 0; jj < 2; ++jj) {
      int j = 2 * wave + jj;
      int R = h2 * 128 + j * 8;
      gload16(bSrc + (size_t)R * ND + t * 64, lds + b * 24576 + 8192 + R * 64 + stDst);
    }
  };
  auto ldA = [&](int b, int mi, int kk) -> short8 {
    return *(const short8*)(lds + b * 24576 + aOff + mi * 1024 + (kk ? ca1 : ca0));
  };
  auto ldB = [&](int b, int ni, int kk) -> short8 {
    return *(const short8*)(lds + b * 24576 + bOff + ni * 1024 + (kk ? ca1 : ca0));
  };

  f32x4 acc[4][4];
  f32x4 z = {0.f, 0.f, 0.f, 0.f};
#pragma unroll
  for (int i = 0; i < 4; ++i)
#pragma unroll
    for (int j = 0; j < 4; ++j) acc[i][j] = z;
  short8 bf00, bf01, bf10, bf11, bf20, bf21, bf30, bf31;

  stageA(0, 0, 0); stageA(1, 0, 0);
  stageB(0, 0, 0); stageB(1, 0, 0);
  stageB(0, 1, 1); stageB(1, 1, 1);
  stageA(0, 1, 1);
  VM5;
  __builtin_amdgcn_s_barrier();

#pragma unroll 1
  for (int it = 0; it < 7; ++it) {
    const int T = 2 * it;
    PHASE1(0, 0, stageA(1, T + 1, 1), NOVM);
    PHASE1(1, 0, stageB(0, T + 2, 0), NOVM);
    PHASE1(2, 0, stageB(1, T + 2, 0), NOVM);
    PHASE1(3, 0, stageA(0, T + 2, 0), VM5);
    PHASE1(0, 1, stageA(1, T + 2, 0), NOVM);
    PHASE1(1, 1, stageB(0, T + 3, 1), NOVM);
    PHASE1(2, 1, stageB(1, T + 3, 1), NOVM);
    PHASE1(3, 1, stageA(0, T + 3, 1), VM5);
  }
  PHASE1(0, 0, stageA(1, 15, 1), NOVM);
  PHASE1(1, 0, NOVM, NOVM);
  PHASE1(2, 0, NOVM, NOVM);
  PHASE1(3, 0, NOVM, VM0);
  PHASE1(0, 1, NOVM, NOVM);
  PHASE1(1, 1, NOVM, NOVM);
  PHASE1(2, 1, NOVM, NOVM);
  PHASE1(3, 1, NOVM, NOVM);

  u16* Mh = Mmat + (size_t)h * ND * ND;
  const int r0 = m0 + wm * 64 + rg * 4;
  const int c0 = n0 + wn * 64 + fr;
#pragma unroll
  for (int mi = 0; mi < 4; ++mi) {
#pragma unroll
    for (int r = 0; r < 4; ++r) {
      u16* orow = Mh + (size_t)(r0 + mi * 16 + r) * ND + c0;
#pragma unroll
      for (int ni = 0; ni < 4; ++ni)
        orow[ni * 16] = f2bf(acc[mi][ni][r]);
    }
  }
}

// ---------------------------------------------------------------------------
// Kernel 5: gemm2_8ph — round-7 exact: rect XCD swizzle (each XCD owns an
// 8m x 8n rectangle), 8-phase core, direct wide-store epilogue. 75.9-76.5 µs.
// ---------------------------------------------------------------------------
__global__ __launch_bounds__(512, 2) void gemm2_8ph(const u16* __restrict__ Xb,
                                                    const u16* __restrict__ Bm,
                                                    const float* __restrict__ Kc,
                                                    float* __restrict__ Out) {
  __shared__ __align__(16) u16 lds[65536];
  const int bid = blockIdx.x;
  const int xcd = bid & 7;
  const int loc = bid >> 3;                         // [0,64)
  const int m0  = (((xcd >> 2) << 3) + (loc >> 3)) * 256;   // 16 m-blocks
  const int n0  = (((xcd & 3) << 3) + (loc & 7)) * 256;     // 32 n-blocks
  GEMM_8PH_BODY(Xb + (size_t)m0 * ND, Bm + (size_t)n0 * ND)

  const int hH = n0 >> 10;
  const int r0 = m0 + wm * 128 + rg * 4;
  const int c0 = n0 + wn * 64 + fr;
  const int o0 = c0 & 1023;
  float bias[4];
#pragma unroll
  for (int ni = 0; ni < 4; ++ni) bias[ni] = Kc[c0 + ni * 16];
#pragma unroll
  for (int mi = 0; mi < 8; ++mi) {
#pragma unroll
    for (int r = 0; r < 4; ++r) {
      int rb = r0 + mi * 16 + r;              // global x row = b*512 + e
      float* orow = Out + ((size_t)(rb >> 9) * 4096 + hH * 512 + (rb & 511)) * 1024 + o0;
#pragma unroll
      for (int ni = 0; ni < 4; ++ni)
        orow[ni * 16] = acc[mi][ni][r] + bias[ni];
    }
  }
}

// ---------------------------------------------------------------------------
extern "C" void kernel_launch(void* const* d_in, const int* in_sizes, int n_in,
                              void* d_out, int out_size, void* d_ws, size_t ws_size,
                              hipStream_t stream) {
  (void)in_sizes; (void)n_in; (void)out_size; (void)ws_size;
  const float* x      = (const float*)d_in[0];
  const float* proj_w = (const float*)d_in[1];
  const float* proj_b = (const float*)d_in[2];
  const float* mix_w  = (const float*)d_in[3];
  const float* mix_b  = (const float*)d_in[4];
  const float* out_w  = (const float*)d_in[5];
  const float* out_b  = (const float*)d_in[6];
  float* Out = (float*)d_out;

  // Scratch carved from d_out (dead before gemm2 writes Out): Wt, Afac
  u16* Wt   = (u16*)d_out;
  u16* Afac = (u16*)d_out + (size_t)8 * 1024 * 1024;
  // Scratch in d_ws: Xb (8 MiB) + Mmat (16 MiB) + Kc (32 KiB)
  u16*   Xb   = (u16*)d_ws;
  u16*   Mmat = (u16*)((char*)d_ws + ((size_t)8 << 20));
  float* Kc   = (float*)((char*)d_ws + ((size_t)24 << 20));

  fused_pre_kernel<<<7168, 256, 0, stream>>>(x, Xb, proj_w, Wt,
                                             out_w, mix_w, mix_b, proj_b, out_b,
                                             Afac, Kc);
  gemm1_8ph<<<dim3(4, 8, NH), 512, 0, stream>>>(Afac, Wt, Mmat);
  gemm2_8ph<<<512, 512, 0, stream>>>(Xb, Mmat, Kc, Out);
}